// Round 6
// baseline (142.315 us; speedup 1.0000x reference)
//
#include <hip/hip_runtime.h>
#include <math.h>

#define E_ 256
#define W_ 20
#define S_ 5
#define Q_ 300
#define D_ 512
#define ALPHA_ 37.0f
#define QCH 32
#define NCH 10           // chunks: 9x32 + 12
#define WPB 10           // w rows per block (2 blocks per e)
#define QPAD 304

typedef __attribute__((ext_vector_type(8))) short bf16x8;
typedef __attribute__((ext_vector_type(4))) float f32x4;
typedef __attribute__((ext_vector_type(2))) unsigned int u32x2;
typedef __attribute__((ext_vector_type(4))) unsigned int u32x4;

// dynamic LDS layout (bytes) — 63 KB => 2 blocks/CU
#define OFF_SS   0         // 16 rows x 1024B : shot_sum bf16 swizzled -> proto_n bf16 (rows 10..15 zero)
#define OFF_XQ   16384     // 32 rows x 1024B : xq chunk bf16 swizzled
#define OFF_BUF  49152     // f32 [10][304]   : -dist -> weights (row stride 1216B, 16B-aligned)
#define OFF_Q2   61312     // f32 [320]       : ||q||^2 (chunk-9 staging writes 288..319)
#define OFF_M2   62592     // f32 [16]        : ||mean||^2 (local w)
#define OFF_MINV 62656     // f32 [16]        : 1/||proto||
#define OFF_RED  62720     // f32 [8][10]     : norm partials
#define LDS_BYTES 63040

__device__ __forceinline__ unsigned short f2bf(float x) {
    unsigned int u = __builtin_bit_cast(unsigned int, x);
    u += 0x7fffu + ((u >> 16) & 1u);          // RNE
    return (unsigned short)(u >> 16);
}
__device__ __forceinline__ float bf2f(unsigned short h) {
    unsigned int u = ((unsigned int)h) << 16;
    return __builtin_bit_cast(float, u);
}

// MFMA fragment read: row-major [row][512 bf16], row stride 1024B,
// 16B chunks XOR-swizzled by (row&7). k0 = bf16 index, multiple of 8.
__device__ __forceinline__ bf16x8 ldfrag(const char* base, int row, int k0) {
    const int phys = (k0 >> 3) ^ (row & 7);
    return *reinterpret_cast<const bf16x8*>(base + row * 1024 + phys * 16);
}

// ---- staging: 32-q chunks; thread (qr=tid>>4, i=tid&15), 4 x 16B per thread ----
__device__ __forceinline__ void stage_load(const float4* xq4, int c, int qcount,
                                           int tid, float4* r) {
    const int qr = tid >> 4;                              // 0..31
    const int i  = tid & 15;
    const int qg = c * QCH + ((qr < qcount) ? qr : 0);    // clamp to in-bounds row
    const float4* row4 = xq4 + (size_t)qg * (D_ / 4);
    #pragma unroll
    for (int j = 0; j < 4; ++j) {
        const int ch = i + 16 * j;                        // 16B chunk 0..63
        r[2 * j]     = row4[2 * ch];
        r[2 * j + 1] = row4[2 * ch + 1];
    }
}

template <bool WQ2>
__device__ __forceinline__ void stage_write(const float4* r, char* s_xq, float* s_q2,
                                            int c, int qcount, int tid) {
    const int qr = tid >> 4;
    const int i  = tid & 15;
    const bool valid = qr < qcount;
    float q2 = 0.f;
    #pragma unroll
    for (int j = 0; j < 4; ++j) {
        const int ch = i + 16 * j;
        float4 a = valid ? r[2 * j]     : make_float4(0.f, 0.f, 0.f, 0.f);
        float4 b = valid ? r[2 * j + 1] : make_float4(0.f, 0.f, 0.f, 0.f);
        if (WQ2) {
            q2 += a.x * a.x + a.y * a.y + a.z * a.z + a.w * a.w
                + b.x * b.x + b.y * b.y + b.z * b.z + b.w * b.w;
        }
        u32x4 v;
        v[0] = (unsigned int)f2bf(a.x) | ((unsigned int)f2bf(a.y) << 16);
        v[1] = (unsigned int)f2bf(a.z) | ((unsigned int)f2bf(a.w) << 16);
        v[2] = (unsigned int)f2bf(b.x) | ((unsigned int)f2bf(b.y) << 16);
        v[3] = (unsigned int)f2bf(b.z) | ((unsigned int)f2bf(b.w) << 16);
        *reinterpret_cast<u32x4*>(s_xq + qr * 1024 + ((ch ^ (qr & 7)) << 4)) = v;
    }
    if (WQ2) {
        q2 += __shfl_xor(q2, 1);
        q2 += __shfl_xor(q2, 2);
        q2 += __shfl_xor(q2, 4);
        q2 += __shfl_xor(q2, 8);
        if (i == 0) s_q2[c * QCH + qr] = valid ? q2 : 0.f;  // up to 319; sized 320
    }
}

__global__ __launch_bounds__(512, 4) void fused6(const float* __restrict__ xs,
                                                 const float* __restrict__ xq,
                                                 const float* __restrict__ temp_p,
                                                 float* __restrict__ out) {
    extern __shared__ char smem[];
    char*  s_ss   = smem + OFF_SS;
    char*  s_xq   = smem + OFF_XQ;
    float* s_buf  = (float*)(smem + OFF_BUF);
    float* s_q2   = (float*)(smem + OFF_Q2);
    float* s_m2   = (float*)(smem + OFF_M2);
    float* s_minv = (float*)(smem + OFF_MINV);
    float* s_red  = (float*)(smem + OFF_RED);

    // XCD-twin mapping: both halves of an e share bid&7 -> same XCD (L2 share)
    const int bid   = blockIdx.x;
    const int o     = bid >> 3;
    const int e     = (bid & 7) * 32 + (o & 31);
    const int wbase = (o >> 5) * WPB;

    const int tid  = threadIdx.x;
    const int lane = tid & 63;
    const int wv   = tid >> 6;
    const int ln15 = lane & 15;
    const int hi   = lane >> 4;

    const float*  xse = xs + (size_t)e * (W_ * S_ * D_);
    const float*  xqe = xq + (size_t)e * (Q_ * D_);
    const float4* xq4 = (const float4*)xqe;
    const float   temp = *temp_p;

    float4 buf[8];

    // prefetch P3 chunk 0
    stage_load(xq4, 0, QCH, tid, buf);

    // ---- P0: zero rows 10..15 of s_ss ----
    {
        const int idx = tid;                 // 384 items < 512
        if (idx < 6 * 64) {
            const int row = WPB + (idx >> 6), ch = idx & 63;
            u32x4 z = {0u, 0u, 0u, 0u};
            *reinterpret_cast<u32x4*>(s_ss + row * 1024 + ch * 16) = z;
        }
    }
    // ---- P1: shot_sum (10 rows) -> s_ss bf16, float4-vectorized ----
    // 1280 float4-outputs: idx -> (lw = idx>>7, dq = idx&127)
    #pragma unroll
    for (int it = 0; it < 3; ++it) {
        const int idx = it * 512 + tid;
        if (idx < WPB * 128) {
            const int lw = idx >> 7;
            const int dq = idx & 127;
            const int w  = wbase + lw;
            const float4* p0 = reinterpret_cast<const float4*>(xse + (w * S_) * D_ + dq * 4);
            float4 a = p0[0];
            #pragma unroll
            for (int s = 1; s < S_; ++s) {
                const float4 t = p0[s * (D_ / 4)];
                a.x += t.x; a.y += t.y; a.z += t.z; a.w += t.w;
            }
            u32x2 v;
            v[0] = (unsigned int)f2bf(a.x) | ((unsigned int)f2bf(a.y) << 16);
            v[1] = (unsigned int)f2bf(a.z) | ((unsigned int)f2bf(a.w) << 16);
            *reinterpret_cast<u32x2*>(s_ss + lw * 1024 + (((dq >> 1) ^ (lw & 7)) << 4) +
                                      (dq & 1) * 8) = v;
        }
    }
    __syncthreads();

    // ---- P2: m2[lw] = ||shot_mean||^2 ----
    for (int lw = wv; lw < WPB; lw += 8) {
        bf16x8 v = *reinterpret_cast<const bf16x8*>(s_ss + lw * 1024 + ((lane ^ (lw & 7)) << 4));
        float p = 0.f;
        #pragma unroll
        for (int j = 0; j < 8; ++j) { float f = bf2f((unsigned short)v[j]); p += f * f; }
        #pragma unroll
        for (int off = 32; off; off >>= 1) p += __shfl_xor(p, off);
        if (lane == 0) s_m2[lw] = p * (1.f / (S_ * S_));
    }
    __syncthreads();

    // ---- P3: dist via MFMA per 32-q chunk -> s_buf[lw][q] = -dist ----
    for (int c = 0; c < NCH; ++c) {
        const int qcount = (c == NCH - 1) ? (Q_ - (NCH - 1) * QCH) : QCH;
        stage_write<true>(buf, s_xq, s_q2, c, qcount, tid);
        __syncthreads();
        if (c + 1 < NCH)
            stage_load(xq4, c + 1, (c + 2 == NCH) ? (Q_ - (NCH - 1) * QCH) : QCH, tid, buf);

        if (wv < 2) {                         // M=16 x N=32 -> 2 tiles, waves 0-1
            const int ntile = wv;
            f32x4 acc = {0.f, 0.f, 0.f, 0.f};
            const int arow = ln15;            // w-local row (M side)
            const int brow = ntile * 16 + ln15;  // q row (N side)
            #pragma unroll
            for (int k = 0; k < 16; ++k) {
                bf16x8 a = ldfrag(s_ss, arow, k * 32 + hi * 8);
                bf16x8 b = ldfrag(s_xq, brow, k * 32 + hi * 8);
                acc = __builtin_amdgcn_mfma_f32_16x16x32_bf16(a, b, acc, 0, 0, 0);
            }
            // C/D layout (HW-verified r3): col(N)=ln15, row(M)=hi*4+r
            const int qloc = ntile * 16 + ln15;
            if (qloc < qcount) {
                const int qg = c * QCH + qloc;
                const float q2v = s_q2[qg];
                #pragma unroll
                for (int r = 0; r < 4; ++r) {
                    const int lw = hi * 4 + r;
                    if (lw < WPB) {
                        float d2 = s_m2[lw] + q2v - 0.4f * acc[r];
                        s_buf[lw * QPAD + qg] = -sqrtf(fmaxf(d2, 0.f));
                    }
                }
            }
        }
        __syncthreads();
    }

    // ---- P4: softmax over q per local w ----
    for (int lw = wv; lw < WPB; lw += 8) {
        float mx = -1e30f;
        for (int q = lane; q < Q_; q += 64) mx = fmaxf(mx, s_buf[lw * QPAD + q]);
        #pragma unroll
        for (int off = 32; off; off >>= 1) mx = fmaxf(mx, __shfl_xor(mx, off));
        float sm = 0.f;
        for (int q = lane; q < Q_; q += 64) {
            float ex = __expf(s_buf[lw * QPAD + q] - mx);
            s_buf[lw * QPAD + q] = ex;
            sm += ex;
        }
        #pragma unroll
        for (int off = 32; off; off >>= 1) sm += __shfl_xor(sm, off);
        const float inv = 1.f / sm;
        for (int q = lane; q < Q_; q += 64) s_buf[lw * QPAD + q] *= inv;
    }
    __syncthreads();

    // prefetch P6 chunk 0 (hides under P5)
    stage_load(xq4, 0, QCH, tid, buf);

    // ---- P5: pooled (d = tid) + proto + norms + proto_n -> s_ss bf16 ----
    {
        float pr[WPB];
        #pragma unroll
        for (int lw = 0; lw < WPB; ++lw) pr[lw] = 0.f;
        for (int q0 = 0; q0 < Q_; q0 += 4) {
            const float qv0 = xqe[(q0 + 0) * D_ + tid];
            const float qv1 = xqe[(q0 + 1) * D_ + tid];
            const float qv2 = xqe[(q0 + 2) * D_ + tid];
            const float qv3 = xqe[(q0 + 3) * D_ + tid];
            #pragma unroll
            for (int lw = 0; lw < WPB; ++lw) {
                const float4 wt = *reinterpret_cast<const float4*>(&s_buf[lw * QPAD + q0]);
                pr[lw] += wt.x * qv0 + wt.y * qv1 + wt.z * qv2 + wt.w * qv3;
            }
        }
        const int chb = tid >> 3;
        #pragma unroll
        for (int lw = 0; lw < WPB; ++lw) {
            unsigned short h =
                *(unsigned short*)(s_ss + lw * 1024 + ((chb ^ (lw & 7)) << 4) + (tid & 7) * 2);
            pr[lw] = (bf2f(h) + ALPHA_ * pr[lw]) * (1.f / (S_ + ALPHA_));
        }
        #pragma unroll
        for (int lw = 0; lw < WPB; ++lw) {
            float p = pr[lw] * pr[lw];
            #pragma unroll
            for (int off = 32; off; off >>= 1) p += __shfl_xor(p, off);
            if (lane == 0) s_red[wv * WPB + lw] = p;
        }
        __syncthreads();
        if (tid < WPB) {
            float p = 0.f;
            #pragma unroll
            for (int k = 0; k < 8; ++k) p += s_red[k * WPB + tid];
            s_minv[tid] = 1.f / fmaxf(sqrtf(p), 1e-12f);
        }
        __syncthreads();
        #pragma unroll
        for (int lw = 0; lw < WPB; ++lw) {
            *(unsigned short*)(s_ss + lw * 1024 + ((chb ^ (lw & 7)) << 4) + (tid & 7) * 2) =
                f2bf(pr[lw] * s_minv[lw]);
        }
        __syncthreads();
    }

    // ---- P6: logits via MFMA per 32-q chunk; direct global store ----
    for (int c = 0; c < NCH; ++c) {
        const int qcount = (c == NCH - 1) ? (Q_ - (NCH - 1) * QCH) : QCH;
        stage_write<false>(buf, s_xq, s_q2, c, qcount, tid);
        __syncthreads();
        if (c + 1 < NCH)
            stage_load(xq4, c + 1, (c + 2 == NCH) ? (Q_ - (NCH - 1) * QCH) : QCH, tid, buf);

        if (wv < 2) {                          // M=32(q) x N=16(w) -> 2 tiles, waves 0-1
            const int mtile = wv;
            f32x4 acc = {0.f, 0.f, 0.f, 0.f};
            const int arow = mtile * 16 + ln15;   // q row (M side)
            const int brow = ln15;                // w-local row (N side, proto_n)
            #pragma unroll
            for (int k = 0; k < 16; ++k) {
                bf16x8 a = ldfrag(s_xq, arow, k * 32 + hi * 8);
                bf16x8 b = ldfrag(s_ss, brow, k * 32 + hi * 8);
                acc = __builtin_amdgcn_mfma_f32_16x16x32_bf16(a, b, acc, 0, 0, 0);
            }
            const int lw = ln15;               // N side
            if (lw < WPB) {
                #pragma unroll
                for (int r = 0; r < 4; ++r) {
                    const int qloc = mtile * 16 + hi * 4 + r;   // M side
                    if (qloc < qcount) {
                        const int qg = c * QCH + qloc;
                        const float scale = temp / fmaxf(sqrtf(s_q2[qg]), 1e-12f);
                        out[(size_t)e * (Q_ * W_) + qg * W_ + wbase + lw] = scale * acc[r];
                    }
                }
            }
        }
        __syncthreads();
    }
}

extern "C" void kernel_launch(void* const* d_in, const int* in_sizes, int n_in,
                              void* d_out, int out_size, void* d_ws, size_t ws_size,
                              hipStream_t stream) {
    const float* xs = (const float*)d_in[0];
    const float* xq = (const float*)d_in[1];
    const float* tp = (const float*)d_in[2];
    hipFuncSetAttribute(reinterpret_cast<const void*>(fused6),
                        hipFuncAttributeMaxDynamicSharedMemorySize, LDS_BYTES);
    fused6<<<2 * E_, 512, LDS_BYTES, stream>>>(xs, xq, tp, (float*)d_out);
}